// Round 4
// baseline (111.015 us; speedup 1.0000x reference)
//
#include <hip/hip_runtime.h>

#define PAD 0
#define CONST_NO 10000
#define Bn 8
#define Sn 64
#define Gn 8
#define Fn 200000
#define Rn 200
#define BMAXn 3
#define KF 64
#define KR 32

// sort geometry: 196 blocks x 1024 facts
#define NBLK 196
#define CHB  1024

// ---- workspace layout (ints) ----
#define WS_STRIDE   128
#define OFF_RES     0                               // 512*128 = 65536
#define OFF_STARTS  (Bn * Sn * WS_STRIDE)           // 65536 (64 ints)
#define OFF_COUNTS  (OFF_STARTS + 64)               // 65600 (64 ints)
#define OFF_CTR     (OFF_COUNTS + 64)               // 65664 (16 ints: per-batch tail ctrs)
#define OFF_BHIST   (OFF_CTR + 16)                  // 65680 (196*64 = 12544)
#define OFF_SORT    78336                           // int4 per fact

__device__ __forceinline__ bool isv(int x) { return x > CONST_NO; }

// ---------- 1) per-block predicate histogram (+ zero tail counters) ----------
__global__ __launch_bounds__(256) void hist_kernel(
    const int* __restrict__ facts, int* __restrict__ ws)
{
    __shared__ int h[64];
    const int t = threadIdx.x;
    if (blockIdx.x == 0 && t < 16) ws[OFF_CTR + t] = 0;
    if (t < 64) h[t] = 0;
    __syncthreads();
    const int f0 = blockIdx.x * CHB + t * 4;
    if (f0 + 3 < Fn) {
        const int4* p4 = (const int4*)(facts + 3 * f0);
        int4 a = p4[0], b4 = p4[1], c4 = p4[2];
        atomicAdd(&h[a.x],  1);
        atomicAdd(&h[a.w],  1);
        atomicAdd(&h[b4.z], 1);
        atomicAdd(&h[c4.y], 1);
    } else {
        #pragma unroll
        for (int u = 0; u < 4; ++u)
            if (f0 + u < Fn) atomicAdd(&h[facts[3 * (f0 + u)]], 1);
    }
    __syncthreads();
    if (t < 64) ws[OFF_BHIST + blockIdx.x * 64 + t] = h[t];
}

// ---------- 2) cross-block scan -> absolute dest bases; starts/counts ----------
__global__ __launch_bounds__(256) void scan_kernel(int* __restrict__ ws)
{
    __shared__ int part[4][64];
    __shared__ int qb[4][64];
    const int t = threadIdx.x;
    const int p = t & 63, q = t >> 6;
    const int b0 = q * 49, b1 = b0 + 49;

    int s = 0;
    for (int b = b0; b < b1; ++b) s += ws[OFF_BHIST + b * 64 + p];
    part[q][p] = s;
    __syncthreads();
    if (t < 64) {
        const int t0 = part[0][t], t1 = part[1][t], t2 = part[2][t], t3 = part[3][t];
        const int tot = t0 + t1 + t2 + t3;
        int incl = tot;
        #pragma unroll
        for (int off = 1; off < 64; off <<= 1) {
            int n = __shfl_up(incl, off, 64);
            if (t >= off) incl += n;
        }
        const int start = incl - tot;
        ws[OFF_STARTS + t] = start;
        ws[OFF_COUNTS + t] = tot;
        qb[0][t] = start;
        qb[1][t] = start + t0;
        qb[2][t] = start + t0 + t1;
        qb[3][t] = start + t0 + t1 + t2;
    }
    __syncthreads();
    int run = qb[q][p];
    for (int b = b0; b < b1; ++b) {
        const int v = ws[OFF_BHIST + b * 64 + p];
        ws[OFF_BHIST + b * 64 + p] = run;     // absolute dest base for (block, pred)
        run += v;
    }
}

// ---------- 3) stable scatter into sorted int4 {a0, a1, idx, 0} ----------
__global__ __launch_bounds__(256) void scatter_kernel(
    const int* __restrict__ facts, int* __restrict__ ws)
{
    __shared__ int predAll[CHB];
    __shared__ int coff[16][64];
    const int t = threadIdx.x;

    for (int k = t; k < 16 * 64; k += 256) ((int*)coff)[k] = 0;

    const int f0 = blockIdx.x * CHB + t * 4;
    int pv[4], a0v[4], a1v[4];
    int nvalid = 0;
    if (f0 + 3 < Fn) {
        const int4* p4 = (const int4*)(facts + 3 * f0);
        int4 a = p4[0], b4 = p4[1], c4 = p4[2];
        pv[0] = a.x;  a0v[0] = a.y;  a1v[0] = a.z;
        pv[1] = a.w;  a0v[1] = b4.x; a1v[1] = b4.y;
        pv[2] = b4.z; a0v[2] = b4.w; a1v[2] = c4.x;
        pv[3] = c4.y; a0v[3] = c4.z; a1v[3] = c4.w;
        nvalid = 4;
    } else {
        #pragma unroll
        for (int u = 0; u < 4; ++u) {
            pv[u] = -1; a0v[u] = 0; a1v[u] = 0;
            if (f0 + u < Fn) {
                pv[u]  = facts[3 * (f0 + u)];
                a0v[u] = facts[3 * (f0 + u) + 1];
                a1v[u] = facts[3 * (f0 + u) + 2];
                nvalid = u + 1;
            }
        }
    }
    const int c = t >> 4;                      // chunk of 64 facts within block
    #pragma unroll
    for (int u = 0; u < 4; ++u) {
        predAll[t * 4 + u] = pv[u];
        if (u < nvalid) atomicAdd(&coff[c][pv[u]], 1);
    }
    __syncthreads();
    if (t < 64) {
        int run = ws[OFF_BHIST + blockIdx.x * 64 + t];
        #pragma unroll
        for (int cc = 0; cc < 16; ++cc) {
            const int v = coff[cc][t];
            coff[cc][t] = run;
            run += v;
        }
    }
    __syncthreads();
    int4* sorted = (int4*)(ws + OFF_SORT);
    const int posb = (t & 15) * 4;
    #pragma unroll
    for (int u = 0; u < 4; ++u) {
        if (u < nvalid) {
            const int p = pv[u];
            int rank = 0;
            for (int j = 0; j < posb + u; ++j)
                rank += (predAll[c * 64 + j] == p);
            sorted[coff[c][p] + rank] = make_int4(a0v[u], a1v[u], f0 + u, 0);
        }
    }
}

// ---------- select phase (runs inside the tail match block of each batch) ----------
__device__ void do_select(
    int b, int t,
    const int* __restrict__ goals, const float* __restrict__ ss,
    const int* __restrict__ facts, const float* __restrict__ fsc,
    const int* __restrict__ heads, const int* __restrict__ bodies,
    const int* __restrict__ rlens, const float* __restrict__ rsc,
    const int* __restrict__ ws, float* __restrict__ outp,
    int* pref, int* nf_s)
{
    if (t < Sn) {
        const int* w = ws + OFF_RES + (b * Sn + t) * WS_STRIDE;
        const int nf = w[0];
        nf_s[t] = nf;
        int val = nf + w[1];
        int incl = val;
        #pragma unroll
        for (int off = 1; off < 64; off <<= 1) {
            int n = __shfl_up(incl, off, 64);
            if (t >= off) incl += n;
        }
        pref[t + 1] = incl;
        if (t == 0) pref[0] = 0;
    }
    __syncthreads();
    const int total = pref[Sn];

    for (int item = t; item < Sn * Gn; item += 256) {
        const int i = item >> 3, g = item & 7;
        int trip[3] = {PAD, PAD, PAD};
        if (i < total) {
            int lo = 0, hi = Sn - 1;
            while (lo < hi) {
                const int mid = (lo + hi) >> 1;
                if (pref[mid + 1] <= i) lo = mid + 1; else hi = mid;
            }
            const int s = lo, j = i - pref[s];
            const int* w = ws + OFF_RES + (b * Sn + s) * WS_STRIDE;
            const int* q = goals + (b * Sn + s) * (Gn * 3);
            const int qa0 = q[1], qa1 = q[2];
            if (j < nf_s[s]) {
                const int fi = w[2 + j];
                const int f1 = facts[3 * fi + 1], f2 = facts[3 * fi + 2];
                if (g >= 1) {
                    #pragma unroll
                    for (int c = 0; c < 3; ++c) {
                        int x = q[g * 3 + c];
                        if (isv(qa0) && x == qa0) x = f1;
                        else if (isv(qa1) && x == qa1) x = f2;
                        trip[c] = x;
                    }
                }
            } else {
                const int ri = w[66 + (j - nf_s[s])];
                const int h1 = heads[3 * ri + 1], h2 = heads[3 * ri + 2];
                const int len = rlens[ri];
                if (g < BMAXn) {
                    if (g < len) {
                        #pragma unroll
                        for (int c = 0; c < 3; ++c) {
                            int x = bodies[(ri * BMAXn + g) * 3 + c];
                            if (isv(h1) && x == h1) x = qa0;
                            if (isv(h2) && x == h2) x = qa1;
                            trip[c] = x;
                        }
                    }
                } else {
                    trip[0] = q[(g - 2) * 3 + 0];
                    trip[1] = q[(g - 2) * 3 + 1];
                    trip[2] = q[(g - 2) * 3 + 2];
                }
            }
        }
        float* o = outp + ((b * Sn + i) * Gn + g) * 3;
        o[0] = (float)trip[0];
        o[1] = (float)trip[1];
        o[2] = (float)trip[2];
    }

    if (t < Sn) {
        const int i = t;
        float sc = 0.f;
        if (i < total) {
            int lo = 0, hi = Sn - 1;
            while (lo < hi) {
                const int mid = (lo + hi) >> 1;
                if (pref[mid + 1] <= i) lo = mid + 1; else hi = mid;
            }
            const int s = lo, j = i - pref[s];
            const int* w = ws + OFF_RES + (b * Sn + s) * WS_STRIDE;
            const float stt = ss[b * Sn + s];
            if (j < nf_s[s]) sc = stt * fsc[w[2 + j]];
            else             sc = stt * rsc[w[66 + (j - nf_s[s])]];
        }
        outp[Bn * Sn * Gn * 3 + b * Sn + t] = sc;
    }
}

// ---------- 4) match (per state) + fused per-batch tail select ----------
__global__ __launch_bounds__(256) void match_select_kernel(
    const int* __restrict__ goals, const float* __restrict__ ss,
    const int* __restrict__ facts, const float* __restrict__ fsc,
    const int* __restrict__ heads, const int* __restrict__ bodies,
    const int* __restrict__ rlens, const float* __restrict__ rsc,
    int* __restrict__ ws, float* __restrict__ outp)
{
    const int state = blockIdx.x;
    const int t = threadIdx.x;
    const int lane = t & 63, wv = t >> 6;
    __shared__ int wave_tot[4];
    __shared__ int sel_flag;
    __shared__ int pref[Sn + 1];
    __shared__ int nf_s[Sn];

    const int* q = goals + state * (Gn * 3);
    const int qp = q[0], qa0 = q[1], qa1 = q[2];
    const bool active = (qp != PAD);
    const bool v0 = isv(qa0), v1 = isv(qa1);
    int* out = ws + OFF_RES + state * WS_STRIDE;

    const int st  = active ? ws[OFF_STARTS + qp] : 0;
    const int cnt = active ? ws[OFF_COUNTS + qp] : 0;
    const int4* S = (const int4*)(ws + OFF_SORT);

    if (v0 && v1) {
        const int n = (cnt < KF) ? cnt : KF;
        if (t < n) out[2 + t] = S[st + t].z;
        if (t == 0) out[0] = n;
    } else {
        int total = 0;
        for (int base = 0; base < cnt && total < KF; base += 512) {
            const int k0 = base + t * 2;
            unsigned mbits = 0;
            int i0 = 0, i1 = 0;
            if (k0 < cnt) {
                const int4 f = S[st + k0];
                i0 = f.z;
                if ((v0 || f.x == qa0) && (v1 || f.y == qa1)) mbits |= 1u;
            }
            if (k0 + 1 < cnt) {
                const int4 f = S[st + k0 + 1];
                i1 = f.z;
                if ((v0 || f.x == qa0) && (v1 || f.y == qa1)) mbits |= 2u;
            }
            const int c2 = __popc(mbits);

            int v = c2;
            #pragma unroll
            for (int off = 1; off < 64; off <<= 1) {
                int n = __shfl_up(v, off, 64);
                if (lane >= off) v += n;
            }
            if (lane == 63) wave_tot[wv] = v;
            __syncthreads();
            int excl = v - c2;
            #pragma unroll
            for (int w = 0; w < 4; ++w) if (w < wv) excl += wave_tot[w];
            const int ctot = wave_tot[0] + wave_tot[1] + wave_tot[2] + wave_tot[3];

            int pos = total + excl;
            if (mbits & 1u) { if (pos < KF) out[2 + pos] = i0; pos++; }
            if (mbits & 2u) { if (pos < KF) out[2 + pos] = i1; }
            total += ctot;
            __syncthreads();
        }
        if (t == 0) out[0] = (total < KF) ? total : KF;
    }

    // rules: first <=32 matches in index order
    int rcnt = 0;
    if (active && t < Rn) {
        const int h0 = heads[3 * t], h1 = heads[3 * t + 1], h2 = heads[3 * t + 2];
        if ((h0 == qp) && (isv(h1) || v0 || qa0 == h1)
                       && (isv(h2) || v1 || qa1 == h2))
            rcnt = 1;
    }
    __syncthreads();
    int v = rcnt;
    #pragma unroll
    for (int off = 1; off < 64; off <<= 1) {
        int n = __shfl_up(v, off, 64);
        if (lane >= off) v += n;
    }
    if (lane == 63) wave_tot[wv] = v;
    __syncthreads();
    int excl = v - rcnt;
    #pragma unroll
    for (int w = 0; w < 4; ++w) if (w < wv) excl += wave_tot[w];
    const int rtot = wave_tot[0] + wave_tot[1] + wave_tot[2] + wave_tot[3];
    if (rcnt && excl < KR) out[66 + excl] = t;
    if (t == 0) out[1] = (rtot < KR) ? rtot : KR;

    // ---- per-batch tail: last finished block of batch b runs select ----
    const int b = state >> 6;
    __syncthreads();                       // all result stores issued & drained
    if (t == 0) {
        __threadfence();                   // device-scope release of our results
        const int old = atomicAdd(ws + OFF_CTR + b, 1);
        sel_flag = (old == Sn - 1);
    }
    __syncthreads();
    if (!sel_flag) return;
    __threadfence();                       // device-scope acquire: see all 64 states
    do_select(b, t, goals, ss, facts, fsc, heads, bodies, rlens, rsc,
              ws, outp, pref, nf_s);
}

extern "C" void kernel_launch(void* const* d_in, const int* in_sizes, int n_in,
                              void* d_out, int out_size, void* d_ws, size_t ws_size,
                              hipStream_t stream) {
    const int*   goals  = (const int*)  d_in[0];
    const float* ss     = (const float*)d_in[1];
    const int*   facts  = (const int*)  d_in[2];
    const float* fsc    = (const float*)d_in[3];
    const int*   heads  = (const int*)  d_in[4];
    const int*   bodies = (const int*)  d_in[5];
    const int*   rlens  = (const int*)  d_in[6];
    const float* rsc    = (const float*)d_in[7];
    int*   ws   = (int*)d_ws;
    float* outp = (float*)d_out;

    hist_kernel        <<<NBLK,    256, 0, stream>>>(facts, ws);
    scan_kernel        <<<1,       256, 0, stream>>>(ws);
    scatter_kernel     <<<NBLK,    256, 0, stream>>>(facts, ws);
    match_select_kernel<<<Bn * Sn, 256, 0, stream>>>(goals, ss, facts, fsc, heads,
                                                     bodies, rlens, rsc, ws, outp);
}

// Round 6
// 95.328 us; speedup vs baseline: 1.1646x; 1.1646x over previous
//
#include <hip/hip_runtime.h>

#define PAD 0
#define CONST_NO 10000
#define Bn 8
#define Sn 64
#define Gn 8
#define Fn 200000
#define Rn 200
#define BMAXn 3
#define KF 64
#define KR 32

// sort geometry: 196 blocks x 1024 facts
#define NBLK 196
#define CHB  1024

// ---- workspace layout (ints) ----
#define WS_STRIDE   128
#define OFF_RES     0                               // 512*128 = 65536
#define OFF_STARTS  (Bn * Sn * WS_STRIDE)           // 65536 (64 ints)
#define OFF_COUNTS  (OFF_STARTS + 64)               // 65600 (64 ints)
#define OFF_BHIST   (OFF_COUNTS + 64)               // 65664 (196*64 = 12544)
#define OFF_SORT    78336                           // int4 per fact (byte off %16==0)

__device__ __forceinline__ bool isv(int x) { return x > CONST_NO; }

// ---------- 1) per-block predicate histogram ----------
__global__ __launch_bounds__(256) void hist_kernel(
    const int* __restrict__ facts, int* __restrict__ ws)
{
    __shared__ int h[64];
    const int t = threadIdx.x;
    if (t < 64) h[t] = 0;
    __syncthreads();
    const int f0 = blockIdx.x * CHB + t * 4;
    if (f0 + 3 < Fn) {
        const int4* p4 = (const int4*)(facts + 3 * f0);
        int4 a = p4[0], b4 = p4[1], c4 = p4[2];
        atomicAdd(&h[a.x],  1);
        atomicAdd(&h[a.w],  1);
        atomicAdd(&h[b4.z], 1);
        atomicAdd(&h[c4.y], 1);
    } else {
        #pragma unroll
        for (int u = 0; u < 4; ++u)
            if (f0 + u < Fn) atomicAdd(&h[facts[3 * (f0 + u)]], 1);
    }
    __syncthreads();
    if (t < 64) ws[OFF_BHIST + blockIdx.x * 64 + t] = h[t];
}

// ---------- 2) stable scatter, with the cross-block scan computed inline ----------
__global__ __launch_bounds__(256) void scatter_kernel(
    const int* __restrict__ facts, int* __restrict__ ws)
{
    __shared__ int predAll[CHB];
    __shared__ int coff[16][64];
    __shared__ int partAll[4][64];
    __shared__ int partPre[4][64];
    const int t = threadIdx.x;
    const int lane = t & 63, wv = t >> 6;
    const int B = blockIdx.x;

    // zero coff FIRST, then the slow scan, then barrier before any atomicAdd
    for (int k = t; k < 16 * 64; k += 256) ((int*)coff)[k] = 0;

    // ---- inline cross-block scan: wave wv sums blocks [wv*49, wv*49+49) ----
    {
        const int b0 = wv * 49, b1 = b0 + 49;
        int sA = 0, sP = 0;
        for (int b = b0; b < b1; ++b) {
            const int v = ws[OFF_BHIST + b * 64 + lane];
            sA += v;
            if (b < B) sP += v;
        }
        partAll[wv][lane] = sA;
        partPre[wv][lane] = sP;
    }

    // ---- load this block's facts (global loads overlap the barrier wait) ----
    const int f0 = B * CHB + t * 4;
    int pv[4], a0v[4], a1v[4];
    int nvalid = 0;
    if (f0 + 3 < Fn) {
        const int4* p4 = (const int4*)(facts + 3 * f0);
        int4 a = p4[0], b4 = p4[1], c4 = p4[2];
        pv[0] = a.x;  a0v[0] = a.y;  a1v[0] = a.z;
        pv[1] = a.w;  a0v[1] = b4.x; a1v[1] = b4.y;
        pv[2] = b4.z; a0v[2] = b4.w; a1v[2] = c4.x;
        pv[3] = c4.y; a0v[3] = c4.z; a1v[3] = c4.w;
        nvalid = 4;
    } else {
        #pragma unroll
        for (int u = 0; u < 4; ++u) {
            pv[u] = -1; a0v[u] = 0; a1v[u] = 0;
            if (f0 + u < Fn) {
                pv[u]  = facts[3 * (f0 + u)];
                a0v[u] = facts[3 * (f0 + u) + 1];
                a1v[u] = facts[3 * (f0 + u) + 2];
                nvalid = u + 1;
            }
        }
    }

    __syncthreads();   // coff fully zeroed before any atomicAdd (R5 crash fix)

    const int c = t >> 4;                      // chunk of 64 facts within block
    #pragma unroll
    for (int u = 0; u < 4; ++u) {
        predAll[t * 4 + u] = pv[u];
        if (u < nvalid) atomicAdd(&coff[c][pv[u]], 1);
    }
    __syncthreads();

    // ---- finish scan: starts + this block's absolute base per predicate ----
    if (t < 64) {
        const int tot = partAll[0][t] + partAll[1][t] + partAll[2][t] + partAll[3][t];
        const int pre = partPre[0][t] + partPre[1][t] + partPre[2][t] + partPre[3][t];
        int incl = tot;
        #pragma unroll
        for (int off = 1; off < 64; off <<= 1) {
            int n = __shfl_up(incl, off, 64);
            if (t >= off) incl += n;
        }
        const int start = incl - tot;
        if (B == 0) {
            ws[OFF_STARTS + t] = start;
            ws[OFF_COUNTS + t] = tot;
        }
        int run = start + pre;
        #pragma unroll
        for (int cc = 0; cc < 16; ++cc) {
            const int v = coff[cc][t];
            coff[cc][t] = run;
            run += v;
        }
    }
    __syncthreads();

    int4* sorted = (int4*)(ws + OFF_SORT);
    const int posb = (t & 15) * 4;
    #pragma unroll
    for (int u = 0; u < 4; ++u) {
        if (u < nvalid) {
            const int p = pv[u];
            int rank = 0;
            for (int j = 0; j < posb + u; ++j)
                rank += (predAll[c * 64 + j] == p);
            sorted[coff[c][p] + rank] = make_int4(a0v[u], a1v[u], f0 + u, 0);
        }
    }
}

// ---------- 3) match: scan only the query predicate's slice ----------
__global__ __launch_bounds__(256) void match_kernel(
    const int* __restrict__ goals, const int* __restrict__ heads,
    int* __restrict__ ws)
{
    const int state = blockIdx.x;
    const int t = threadIdx.x;
    const int lane = t & 63, wv = t >> 6;
    __shared__ int wave_tot[4];

    const int* q = goals + state * (Gn * 3);
    const int qp = q[0], qa0 = q[1], qa1 = q[2];
    const bool active = (qp != PAD);
    const bool v0 = isv(qa0), v1 = isv(qa1);
    int* out = ws + OFF_RES + state * WS_STRIDE;

    const int st  = active ? ws[OFF_STARTS + qp] : 0;
    const int cnt = active ? ws[OFF_COUNTS + qp] : 0;
    const int4* S = (const int4*)(ws + OFF_SORT);

    if (v0 && v1) {
        const int n = (cnt < KF) ? cnt : KF;
        if (t < n) out[2 + t] = S[st + t].z;
        if (t == 0) out[0] = n;
    } else {
        int total = 0;
        for (int base = 0; base < cnt && total < KF; base += 1024) {
            const int k0 = base + t * 4;
            unsigned mbits = 0;
            int idxv[4];
            #pragma unroll
            for (int u = 0; u < 4; ++u) {
                idxv[u] = 0;
                if (k0 + u < cnt) {
                    const int4 f = S[st + k0 + u];
                    idxv[u] = f.z;
                    if ((v0 || f.x == qa0) && (v1 || f.y == qa1)) mbits |= (1u << u);
                }
            }
            const int c4 = __popc(mbits);

            int v = c4;
            #pragma unroll
            for (int off = 1; off < 64; off <<= 1) {
                int n = __shfl_up(v, off, 64);
                if (lane >= off) v += n;
            }
            if (lane == 63) wave_tot[wv] = v;
            __syncthreads();
            int excl = v - c4;
            #pragma unroll
            for (int w = 0; w < 4; ++w) if (w < wv) excl += wave_tot[w];
            const int ctot = wave_tot[0] + wave_tot[1] + wave_tot[2] + wave_tot[3];

            int pos = total + excl;
            #pragma unroll
            for (int u = 0; u < 4; ++u) {
                if (mbits & (1u << u)) {
                    if (pos < KF) out[2 + pos] = idxv[u];
                    pos++;
                }
            }
            total += ctot;
            __syncthreads();
        }
        if (t == 0) out[0] = (total < KF) ? total : KF;
    }

    // rules: first <=32 matches in index order
    int rcnt = 0;
    if (active && t < Rn) {
        const int h0 = heads[3 * t], h1 = heads[3 * t + 1], h2 = heads[3 * t + 2];
        if ((h0 == qp) && (isv(h1) || v0 || qa0 == h1)
                       && (isv(h2) || v1 || qa1 == h2))
            rcnt = 1;
    }
    __syncthreads();
    int v = rcnt;
    #pragma unroll
    for (int off = 1; off < 64; off <<= 1) {
        int n = __shfl_up(v, off, 64);
        if (lane >= off) v += n;
    }
    if (lane == 63) wave_tot[wv] = v;
    __syncthreads();
    int excl = v - rcnt;
    #pragma unroll
    for (int w = 0; w < 4; ++w) if (w < wv) excl += wave_tot[w];
    const int rtot = wave_tot[0] + wave_tot[1] + wave_tot[2] + wave_tot[3];
    if (rcnt && excl < KR) out[66 + excl] = t;
    if (t == 0) out[1] = (rtot < KR) ? rtot : KR;
}

// ---------- 4) select: 8 slice-blocks per batch ----------
__global__ __launch_bounds__(256) void select_kernel(
    const int* __restrict__ goals, const float* __restrict__ ss,
    const int* __restrict__ facts, const float* __restrict__ fsc,
    const int* __restrict__ heads, const int* __restrict__ bodies,
    const int* __restrict__ rlens, const float* __restrict__ rsc,
    const int* __restrict__ ws, float* __restrict__ outp)
{
    const int b = blockIdx.x >> 3;          // batch
    const int k = blockIdx.x & 7;           // slice: slots [k*8, k*8+8)
    const int t = threadIdx.x;
    __shared__ int pref[Sn + 1];
    __shared__ int nf_s[Sn];

    if (t < Sn) {
        const int* w = ws + OFF_RES + (b * Sn + t) * WS_STRIDE;
        const int nf = w[0];
        nf_s[t] = nf;
        int val = nf + w[1];
        int incl = val;
        #pragma unroll
        for (int off = 1; off < 64; off <<= 1) {
            int n = __shfl_up(incl, off, 64);
            if (t >= off) incl += n;
        }
        pref[t + 1] = incl;
        if (t == 0) pref[0] = 0;
    }
    __syncthreads();
    const int total = pref[Sn];

    // 8 slots x 8 goal-positions = 64 (i,g) pairs, one per thread t<64
    if (t < 64) {
        const int i = k * 8 + (t >> 3), g = t & 7;
        int trip[3] = {PAD, PAD, PAD};
        if (i < total) {
            int lo = 0, hi = Sn - 1;
            while (lo < hi) {
                const int mid = (lo + hi) >> 1;
                if (pref[mid + 1] <= i) lo = mid + 1; else hi = mid;
            }
            const int s = lo, j = i - pref[s];
            const int* w = ws + OFF_RES + (b * Sn + s) * WS_STRIDE;
            const int* q = goals + (b * Sn + s) * (Gn * 3);
            const int qa0 = q[1], qa1 = q[2];
            if (j < nf_s[s]) {
                const int fi = w[2 + j];
                const int f1 = facts[3 * fi + 1], f2 = facts[3 * fi + 2];
                if (g >= 1) {
                    #pragma unroll
                    for (int c = 0; c < 3; ++c) {
                        int x = q[g * 3 + c];
                        if (isv(qa0) && x == qa0) x = f1;
                        else if (isv(qa1) && x == qa1) x = f2;
                        trip[c] = x;
                    }
                }
            } else {
                const int ri = w[66 + (j - nf_s[s])];
                const int h1 = heads[3 * ri + 1], h2 = heads[3 * ri + 2];
                const int len = rlens[ri];
                if (g < BMAXn) {
                    if (g < len) {
                        #pragma unroll
                        for (int c = 0; c < 3; ++c) {
                            int x = bodies[(ri * BMAXn + g) * 3 + c];
                            if (isv(h1) && x == h1) x = qa0;
                            if (isv(h2) && x == h2) x = qa1;
                            trip[c] = x;
                        }
                    }
                } else {
                    trip[0] = q[(g - 2) * 3 + 0];
                    trip[1] = q[(g - 2) * 3 + 1];
                    trip[2] = q[(g - 2) * 3 + 2];
                }
            }
        }
        float* o = outp + ((b * Sn + i) * Gn + g) * 3;
        o[0] = (float)trip[0];
        o[1] = (float)trip[1];
        o[2] = (float)trip[2];
    } else if (t >= 128 && t < 136) {
        // scores for this slice's 8 slots
        const int i = k * 8 + (t - 128);
        float sc = 0.f;
        if (i < total) {
            int lo = 0, hi = Sn - 1;
            while (lo < hi) {
                const int mid = (lo + hi) >> 1;
                if (pref[mid + 1] <= i) lo = mid + 1; else hi = mid;
            }
            const int s = lo, j = i - pref[s];
            const int* w = ws + OFF_RES + (b * Sn + s) * WS_STRIDE;
            const float stt = ss[b * Sn + s];
            if (j < nf_s[s]) sc = stt * fsc[w[2 + j]];
            else             sc = stt * rsc[w[66 + (j - nf_s[s])]];
        }
        outp[Bn * Sn * Gn * 3 + b * Sn + i] = sc;
    }
}

extern "C" void kernel_launch(void* const* d_in, const int* in_sizes, int n_in,
                              void* d_out, int out_size, void* d_ws, size_t ws_size,
                              hipStream_t stream) {
    const int*   goals  = (const int*)  d_in[0];
    const float* ss     = (const float*)d_in[1];
    const int*   facts  = (const int*)  d_in[2];
    const float* fsc    = (const float*)d_in[3];
    const int*   heads  = (const int*)  d_in[4];
    const int*   bodies = (const int*)  d_in[5];
    const int*   rlens  = (const int*)  d_in[6];
    const float* rsc    = (const float*)d_in[7];
    int*   ws   = (int*)d_ws;
    float* outp = (float*)d_out;

    hist_kernel   <<<NBLK,    256, 0, stream>>>(facts, ws);
    scatter_kernel<<<NBLK,    256, 0, stream>>>(facts, ws);
    match_kernel  <<<Bn * Sn, 256, 0, stream>>>(goals, heads, ws);
    select_kernel <<<Bn * 8,  256, 0, stream>>>(goals, ss, facts, fsc, heads,
                                                bodies, rlens, rsc, ws, outp);
}

// Round 7
// 93.723 us; speedup vs baseline: 1.1845x; 1.0171x over previous
//
#include <hip/hip_runtime.h>

#define PAD 0
#define CONST_NO 10000
#define Bn 8
#define Sn 64
#define Gn 8
#define Fn 200000
#define Rn 200
#define BMAXn 3
#define KF 64
#define KR 32

// sort geometry: 98 blocks x 2048 facts (32 chunks of 64)
#define NBLK 98
#define CHB  2048

// ---- workspace layout (ints) ----
#define WS_STRIDE   128
#define OFF_RES     0                               // 512*128 = 65536
#define OFF_STARTS  (Bn * Sn * WS_STRIDE)           // 65536 (64 ints)
#define OFF_COUNTS  (OFF_STARTS + 64)               // 65600 (64 ints)
#define OFF_BHIST   (OFF_COUNTS + 64)               // 65664 (98*64 = 6272)
#define OFF_SORT    71936                           // int2 per fact (byte off %16==0)

__device__ __forceinline__ bool isv(int x) { return x > CONST_NO; }

// same-predicate lane mask via 6 ballots (preds are 1..50 < 64; OOB lanes use p=-1
// which is excluded because every valid p<63 has a zero bit among bits 0..5)
__device__ __forceinline__ unsigned long long same_pred_mask(int p, unsigned long long valid)
{
    unsigned long long mask = valid;
    #pragma unroll
    for (int bit = 0; bit < 6; ++bit) {
        const unsigned long long b = __ballot((p >> bit) & 1);
        mask &= ((p >> bit) & 1) ? b : ~b;
    }
    return mask;
}

// ---------- 1) per-block predicate histogram (ballot-based, no atomics) ----------
__global__ __launch_bounds__(256) void hist_kernel(
    const int* __restrict__ facts, int* __restrict__ ws)
{
    __shared__ int cnt[32][64];                     // 8 KB
    const int t = threadIdx.x, lane = t & 63, wv = t >> 6;
    const int B = blockIdx.x;

    for (int k = t; k < 32 * 64; k += 256) ((int*)cnt)[k] = 0;

    // preload this wave's 8 chunks of predicates
    int pv[8];
    #pragma unroll
    for (int k = 0; k < 8; ++k) {
        const int c = wv * 8 + k;
        const int i = B * CHB + c * 64 + lane;
        pv[k] = (i < Fn) ? facts[3 * i] : -1;
    }
    __syncthreads();                                // cnt zeroed before leader writes

    const unsigned long long lmlt = (1ull << lane) - 1ull;
    #pragma unroll
    for (int k = 0; k < 8; ++k) {
        const int c = wv * 8 + k;
        const unsigned long long valid = __ballot(pv[k] >= 0);
        const unsigned long long mask = same_pred_mask(pv[k], valid);
        if (pv[k] >= 0 && (mask & lmlt) == 0)       // leader lane for this pred
            cnt[c][pv[k]] = (int)__popcll(mask);
    }
    __syncthreads();
    if (t < 64) {
        int s = 0;
        #pragma unroll
        for (int c = 0; c < 32; ++c) s += cnt[c][t];
        ws[OFF_BHIST + B * 64 + t] = s;
    }
}

// ---------- 2) stable scatter with inline cross-block scan ----------
__global__ __launch_bounds__(256) void scatter_kernel(
    const int* __restrict__ facts, int* __restrict__ ws)
{
    __shared__ int cnt[32][64];                     // per-chunk counts -> bases
    __shared__ int partAll[4][64];
    __shared__ int partPre[4][64];
    const int t = threadIdx.x, lane = t & 63, wv = t >> 6;
    const int B = blockIdx.x;

    for (int k = t; k < 32 * 64; k += 256) ((int*)cnt)[k] = 0;

    // inline cross-block scan: wave wv sums rows [wv*25, min(98, wv*25+25))
    {
        const int b0 = wv * 25, b1 = (b0 + 25 < NBLK) ? b0 + 25 : NBLK;
        int sA = 0, sP = 0;
        for (int b = b0; b < b1; ++b) {
            const int v = ws[OFF_BHIST + b * 64 + lane];
            sA += v;
            if (b < B) sP += v;
        }
        partAll[wv][lane] = sA;
        partPre[wv][lane] = sP;
    }

    // preload this wave's 8 chunks
    int pv[8], pk[8];
    #pragma unroll
    for (int k = 0; k < 8; ++k) {
        const int c = wv * 8 + k;
        const int i = B * CHB + c * 64 + lane;
        int p = -1, a0 = 0, a1 = 0;
        if (i < Fn) {
            p  = facts[3 * i];
            a0 = facts[3 * i + 1];
            a1 = facts[3 * i + 2];
        }
        pv[k] = p;
        pk[k] = (a0 << 14) | a1;                    // args < 2^14
    }
    __syncthreads();                                // cnt zeroed before leader writes

    const unsigned long long lmlt = (1ull << lane) - 1ull;
    int rk[8];
    #pragma unroll
    for (int k = 0; k < 8; ++k) {
        const int c = wv * 8 + k;
        const unsigned long long valid = __ballot(pv[k] >= 0);
        const unsigned long long mask = same_pred_mask(pv[k], valid);
        rk[k] = (int)__popcll(mask & lmlt);
        if (pv[k] >= 0 && (mask & lmlt) == 0)
            cnt[c][pv[k]] = (int)__popcll(mask);
    }
    __syncthreads();

    // per-(chunk,pred) absolute bases; block 0 publishes starts/counts
    if (t < 64) {
        const int tot = partAll[0][t] + partAll[1][t] + partAll[2][t] + partAll[3][t];
        const int pre = partPre[0][t] + partPre[1][t] + partPre[2][t] + partPre[3][t];
        int incl = tot;
        #pragma unroll
        for (int off = 1; off < 64; off <<= 1) {
            int n = __shfl_up(incl, off, 64);
            if (t >= off) incl += n;
        }
        const int start = incl - tot;
        if (B == 0) {
            ws[OFF_STARTS + t] = start;
            ws[OFF_COUNTS + t] = tot;
        }
        int run = start + pre;
        #pragma unroll
        for (int c = 0; c < 32; ++c) {
            const int v = cnt[c][t];
            cnt[c][t] = run;
            run += v;
        }
    }
    __syncthreads();

    int2* sorted = (int2*)(ws + OFF_SORT);
    #pragma unroll
    for (int k = 0; k < 8; ++k) {
        if (pv[k] >= 0) {
            const int c = wv * 8 + k;
            const int i = B * CHB + c * 64 + lane;
            sorted[cnt[c][pv[k]] + rk[k]] = make_int2(pk[k], i);
        }
    }
}

// ---------- 3) match: scan only the query predicate's slice ----------
__global__ __launch_bounds__(256) void match_kernel(
    const int* __restrict__ goals, const int* __restrict__ heads,
    int* __restrict__ ws)
{
    const int state = blockIdx.x;
    const int t = threadIdx.x;
    const int lane = t & 63, wv = t >> 6;
    __shared__ int wave_tot[4];

    const int* q = goals + state * (Gn * 3);
    const int qp = q[0], qa0 = q[1], qa1 = q[2];
    const bool active = (qp != PAD);
    const bool v0 = isv(qa0), v1 = isv(qa1);
    int* out = ws + OFF_RES + state * WS_STRIDE;

    const int st  = active ? ws[OFF_STARTS + qp] : 0;
    const int cnt = active ? ws[OFF_COUNTS + qp] : 0;
    const int2* S = (const int2*)(ws + OFF_SORT);

    if (v0 && v1) {
        const int n = (cnt < KF) ? cnt : KF;
        if (t < n) out[2 + t] = S[st + t].y;
        if (t == 0) out[0] = n;
    } else {
        const int qv = (v0 ? 0 : (qa0 << 14)) | (v1 ? 0 : qa1);
        const int qm = (v0 ? 0 : (0x3FFF << 14)) | (v1 ? 0 : 0x3FFF);
        int total = 0;
        for (int base = 0; base < cnt && total < KF; base += 1024) {
            const int k0 = base + t * 4;
            unsigned mbits = 0;
            int idxv[4];
            #pragma unroll
            for (int u = 0; u < 4; ++u) {
                idxv[u] = 0;
                if (k0 + u < cnt) {
                    const int2 f = S[st + k0 + u];
                    idxv[u] = f.y;
                    if (((f.x ^ qv) & qm) == 0) mbits |= (1u << u);
                }
            }
            const int c4 = __popc(mbits);

            int v = c4;
            #pragma unroll
            for (int off = 1; off < 64; off <<= 1) {
                int n = __shfl_up(v, off, 64);
                if (lane >= off) v += n;
            }
            if (lane == 63) wave_tot[wv] = v;
            __syncthreads();
            int excl = v - c4;
            #pragma unroll
            for (int w = 0; w < 4; ++w) if (w < wv) excl += wave_tot[w];
            const int ctot = wave_tot[0] + wave_tot[1] + wave_tot[2] + wave_tot[3];

            int pos = total + excl;
            #pragma unroll
            for (int u = 0; u < 4; ++u) {
                if (mbits & (1u << u)) {
                    if (pos < KF) out[2 + pos] = idxv[u];
                    pos++;
                }
            }
            total += ctot;
            __syncthreads();
        }
        if (t == 0) out[0] = (total < KF) ? total : KF;
    }

    // rules: first <=32 matches in index order
    int rcnt = 0;
    if (active && t < Rn) {
        const int h0 = heads[3 * t], h1 = heads[3 * t + 1], h2 = heads[3 * t + 2];
        if ((h0 == qp) && (isv(h1) || v0 || qa0 == h1)
                       && (isv(h2) || v1 || qa1 == h2))
            rcnt = 1;
    }
    __syncthreads();
    int v = rcnt;
    #pragma unroll
    for (int off = 1; off < 64; off <<= 1) {
        int n = __shfl_up(v, off, 64);
        if (lane >= off) v += n;
    }
    if (lane == 63) wave_tot[wv] = v;
    __syncthreads();
    int excl = v - rcnt;
    #pragma unroll
    for (int w = 0; w < 4; ++w) if (w < wv) excl += wave_tot[w];
    const int rtot = wave_tot[0] + wave_tot[1] + wave_tot[2] + wave_tot[3];
    if (rcnt && excl < KR) out[66 + excl] = t;
    if (t == 0) out[1] = (rtot < KR) ? rtot : KR;
}

// ---------- 4) select: 8 slice-blocks per batch ----------
__global__ __launch_bounds__(256) void select_kernel(
    const int* __restrict__ goals, const float* __restrict__ ss,
    const int* __restrict__ facts, const float* __restrict__ fsc,
    const int* __restrict__ heads, const int* __restrict__ bodies,
    const int* __restrict__ rlens, const float* __restrict__ rsc,
    const int* __restrict__ ws, float* __restrict__ outp)
{
    const int b = blockIdx.x >> 3;          // batch
    const int k = blockIdx.x & 7;           // slice: slots [k*8, k*8+8)
    const int t = threadIdx.x;
    __shared__ int pref[Sn + 1];
    __shared__ int nf_s[Sn];

    if (t < Sn) {
        const int* w = ws + OFF_RES + (b * Sn + t) * WS_STRIDE;
        const int nf = w[0];
        nf_s[t] = nf;
        int val = nf + w[1];
        int incl = val;
        #pragma unroll
        for (int off = 1; off < 64; off <<= 1) {
            int n = __shfl_up(incl, off, 64);
            if (t >= off) incl += n;
        }
        pref[t + 1] = incl;
        if (t == 0) pref[0] = 0;
    }
    __syncthreads();
    const int total = pref[Sn];

    if (t < 64) {
        const int i = k * 8 + (t >> 3), g = t & 7;
        int trip[3] = {PAD, PAD, PAD};
        if (i < total) {
            int lo = 0, hi = Sn - 1;
            while (lo < hi) {
                const int mid = (lo + hi) >> 1;
                if (pref[mid + 1] <= i) lo = mid + 1; else hi = mid;
            }
            const int s = lo, j = i - pref[s];
            const int* w = ws + OFF_RES + (b * Sn + s) * WS_STRIDE;
            const int* q = goals + (b * Sn + s) * (Gn * 3);
            const int qa0 = q[1], qa1 = q[2];
            if (j < nf_s[s]) {
                const int fi = w[2 + j];
                const int f1 = facts[3 * fi + 1], f2 = facts[3 * fi + 2];
                if (g >= 1) {
                    #pragma unroll
                    for (int c = 0; c < 3; ++c) {
                        int x = q[g * 3 + c];
                        if (isv(qa0) && x == qa0) x = f1;
                        else if (isv(qa1) && x == qa1) x = f2;
                        trip[c] = x;
                    }
                }
            } else {
                const int ri = w[66 + (j - nf_s[s])];
                const int h1 = heads[3 * ri + 1], h2 = heads[3 * ri + 2];
                const int len = rlens[ri];
                if (g < BMAXn) {
                    if (g < len) {
                        #pragma unroll
                        for (int c = 0; c < 3; ++c) {
                            int x = bodies[(ri * BMAXn + g) * 3 + c];
                            if (isv(h1) && x == h1) x = qa0;
                            if (isv(h2) && x == h2) x = qa1;
                            trip[c] = x;
                        }
                    }
                } else {
                    trip[0] = q[(g - 2) * 3 + 0];
                    trip[1] = q[(g - 2) * 3 + 1];
                    trip[2] = q[(g - 2) * 3 + 2];
                }
            }
        }
        float* o = outp + ((b * Sn + i) * Gn + g) * 3;
        o[0] = (float)trip[0];
        o[1] = (float)trip[1];
        o[2] = (float)trip[2];
    } else if (t >= 128 && t < 136) {
        const int i = k * 8 + (t - 128);
        float sc = 0.f;
        if (i < total) {
            int lo = 0, hi = Sn - 1;
            while (lo < hi) {
                const int mid = (lo + hi) >> 1;
                if (pref[mid + 1] <= i) lo = mid + 1; else hi = mid;
            }
            const int s = lo, j = i - pref[s];
            const int* w = ws + OFF_RES + (b * Sn + s) * WS_STRIDE;
            const float stt = ss[b * Sn + s];
            if (j < nf_s[s]) sc = stt * fsc[w[2 + j]];
            else             sc = stt * rsc[w[66 + (j - nf_s[s])]];
        }
        outp[Bn * Sn * Gn * 3 + b * Sn + i] = sc;
    }
}

extern "C" void kernel_launch(void* const* d_in, const int* in_sizes, int n_in,
                              void* d_out, int out_size, void* d_ws, size_t ws_size,
                              hipStream_t stream) {
    const int*   goals  = (const int*)  d_in[0];
    const float* ss     = (const float*)d_in[1];
    const int*   facts  = (const int*)  d_in[2];
    const float* fsc    = (const float*)d_in[3];
    const int*   heads  = (const int*)  d_in[4];
    const int*   bodies = (const int*)  d_in[5];
    const int*   rlens  = (const int*)  d_in[6];
    const float* rsc    = (const float*)d_in[7];
    int*   ws   = (int*)d_ws;
    float* outp = (float*)d_out;

    hist_kernel   <<<NBLK,    256, 0, stream>>>(facts, ws);
    scatter_kernel<<<NBLK,    256, 0, stream>>>(facts, ws);
    match_kernel  <<<Bn * Sn, 256, 0, stream>>>(goals, heads, ws);
    select_kernel <<<Bn * 8,  256, 0, stream>>>(goals, ss, facts, fsc, heads,
                                                bodies, rlens, rsc, ws, outp);
}

// Round 8
// 90.507 us; speedup vs baseline: 1.2266x; 1.0355x over previous
//
#include <hip/hip_runtime.h>

#define PAD 0
#define CONST_NO 10000
#define Bn 8
#define Sn 64
#define Gn 8
#define Fn 200000
#define Rn 200
#define BMAXn 3
#define KF 64
#define KR 32

#define NBLK 196
#define CHB  1024

// ---- workspace layout (ints) ----
#define OFF_CNTF   0                    // 512: per-state unordered match count
#define OFF_PN     512                  // 64 : per-predicate min(count,64)
#define OFF_PFIRST 1024                 // 64*64: first-64 fact idx per predicate
#define OFF_UF     5120                 // 512*64: unordered fact idx per state

__device__ __forceinline__ bool isv(int x) { return x > CONST_NO; }

// ---------- fused: blocks [0,196) probe facts vs const-queries;
//                   blocks [196,246) collect first-64 per predicate ----------
__global__ __launch_bounds__(256) void probe_kernel(
    const int* __restrict__ goals, const int* __restrict__ facts,
    int* __restrict__ ws)
{
    const int t = threadIdx.x;
    const int lane = t & 63, wv = t >> 6;

    if (blockIdx.x < NBLK) {
        // ================= probe role =================
        __shared__ int4 qlist[512];
        __shared__ int qcnt[64], qstart[64];
        const int B = blockIdx.x;

        if (t < 64) qcnt[t] = 0;
        __syncthreads();

        // stage the 512 queries, bucketed by predicate (const-arg queries only)
        int myPos[2], myQp[2], myQv[2], myQm[2], mySt[2];
        #pragma unroll
        for (int k = 0; k < 2; ++k) {
            const int s = t + k * 256;
            const int* q = goals + s * (Gn * 3);
            const int qp = q[0], qa0 = q[1], qa1 = q[2];
            const bool v0 = isv(qa0), v1 = isv(qa1);
            const bool use = (qp != PAD) && !(v0 && v1);
            myQp[k] = use ? qp : -1;
            myQv[k] = (v0 ? 0 : (qa0 << 14)) | (v1 ? 0 : qa1);
            myQm[k] = (v0 ? 0 : (0x3FFF << 14)) | (v1 ? 0 : 0x3FFF);
            mySt[k] = s;
            myPos[k] = use ? atomicAdd(&qcnt[qp], 1) : -1;
        }
        __syncthreads();
        if (t < 64) {
            const int v = qcnt[t];
            int incl = v;
            #pragma unroll
            for (int off = 1; off < 64; off <<= 1) {
                int n = __shfl_up(incl, off, 64);
                if (t >= off) incl += n;
            }
            qstart[t] = incl - v;
        }
        __syncthreads();
        #pragma unroll
        for (int k = 0; k < 2; ++k)
            if (myQp[k] >= 0)
                qlist[qstart[myQp[k]] + myPos[k]] =
                    make_int4(myQv[k], myQm[k], mySt[k], 0);
        __syncthreads();

        // stream this block's 1024 facts; compare against the predicate bucket
        const int f0 = B * CHB + t * 4;
        int pv[4], pk[4];
        if (f0 + 3 < Fn) {
            const int4* p4 = (const int4*)(facts + 3 * f0);
            int4 a = p4[0], b4 = p4[1], c4 = p4[2];
            pv[0] = a.x;  pk[0] = (a.y  << 14) | a.z;
            pv[1] = a.w;  pk[1] = (b4.x << 14) | b4.y;
            pv[2] = b4.z; pk[2] = (b4.w << 14) | c4.x;
            pv[3] = c4.y; pk[3] = (c4.z << 14) | c4.w;
        } else {
            #pragma unroll
            for (int u = 0; u < 4; ++u) {
                pv[u] = -1; pk[u] = 0;
                if (f0 + u < Fn) {
                    pv[u] = facts[3 * (f0 + u)];
                    pk[u] = (facts[3 * (f0 + u) + 1] << 14) | facts[3 * (f0 + u) + 2];
                }
            }
        }
        #pragma unroll
        for (int u = 0; u < 4; ++u) {
            if (pv[u] >= 0) {
                const int j0 = qstart[pv[u]], j1 = j0 + qcnt[pv[u]];
                for (int j = j0; j < j1; ++j) {
                    const int4 qq = qlist[j];
                    if (((pk[u] ^ qq.x) & qq.y) == 0) {
                        const int pos = atomicAdd(ws + OFF_CNTF + qq.z, 1);
                        if (pos < KF) ws[OFF_UF + qq.z * KF + pos] = f0 + u;
                    }
                }
            }
        }
    } else {
        // ================= first-64-per-predicate role =================
        __shared__ int wave_tot[4];
        const int p = blockIdx.x - NBLK + 1;       // predicate 1..50

        int total = 0;
        for (int base = 0; base < Fn && total < KF; base += 1024) {
            const int f0 = base + t * 4;
            unsigned mbits = 0;
            if (f0 + 3 < Fn) {
                const int4* p4 = (const int4*)(facts + 3 * f0);
                int4 a = p4[0], b4 = p4[1], c4 = p4[2];
                if (a.x  == p) mbits |= 1u;
                if (a.w  == p) mbits |= 2u;
                if (b4.z == p) mbits |= 4u;
                if (c4.y == p) mbits |= 8u;
            } else {
                #pragma unroll
                for (int u = 0; u < 4; ++u)
                    if (f0 + u < Fn && facts[3 * (f0 + u)] == p) mbits |= (1u << u);
            }
            const int c4n = __popc(mbits);

            int v = c4n;
            #pragma unroll
            for (int off = 1; off < 64; off <<= 1) {
                int n = __shfl_up(v, off, 64);
                if (lane >= off) v += n;
            }
            if (lane == 63) wave_tot[wv] = v;
            __syncthreads();
            int excl = v - c4n;
            #pragma unroll
            for (int w = 0; w < 4; ++w) if (w < wv) excl += wave_tot[w];
            const int ctot = wave_tot[0] + wave_tot[1] + wave_tot[2] + wave_tot[3];

            int pos = total + excl;
            #pragma unroll
            for (int u = 0; u < 4; ++u) {
                if (mbits & (1u << u)) {
                    if (pos < KF) ws[OFF_PFIRST + p * 64 + pos] = f0 + u;
                    pos++;
                }
            }
            total += ctot;
            __syncthreads();
        }
        if (t == 0) ws[OFF_PN + p] = (total < KF) ? total : KF;
    }
}

// ---------- finalize + select: one block per batch ----------
__global__ __launch_bounds__(256) void finalize_kernel(
    const int* __restrict__ goals, const float* __restrict__ ss,
    const int* __restrict__ facts, const float* __restrict__ fsc,
    const int* __restrict__ heads, const int* __restrict__ bodies,
    const int* __restrict__ rlens, const float* __restrict__ rsc,
    const int* __restrict__ ws, float* __restrict__ outp)
{
    __shared__ int sfx[Sn * 64];        // 16 KB: sorted fact idx (const states)
    __shared__ int seg[4][Sn][16];      // 16 KB: rule segments (50 rules each)
    __shared__ int segc[4][Sn];
    __shared__ int hds[Rn * 3];
    __shared__ int pref[Sn + 1];
    __shared__ int nfs[Sn], nrs[Sn], vvf[Sn], qps[Sn];

    const int b = blockIdx.x, t = threadIdx.x;
    const int lane = t & 63, wv = t >> 6;

    for (int k = t; k < Rn * 3; k += 256) hds[k] = heads[k];
    segc[wv][lane] = 0;   // 4*64 == 256 == blockDim
    __syncthreads();

    // rules: wave wv checks rules [wv*50, wv*50+50) for state s=lane
    {
        const int s = lane;
        const int* q = goals + (b * Sn + s) * (Gn * 3);
        const int qp = q[0], qa0 = q[1], qa1 = q[2];
        const bool v0 = isv(qa0), v1 = isv(qa1);
        const bool active = (qp != PAD);
        int cnt = 0;
        const int r0 = wv * 50;
        for (int r = r0; r < r0 + 50; ++r) {
            const int h0 = hds[3 * r], h1 = hds[3 * r + 1], h2 = hds[3 * r + 2];
            if (active && h0 == qp && (isv(h1) || v0 || qa0 == h1)
                                   && (isv(h2) || v1 || qa1 == h2)) {
                if (cnt < 16) seg[wv][s][cnt] = r;
                cnt++;
            }
        }
        segc[wv][s] = (cnt < 16) ? cnt : 16;
    }
    __syncthreads();

    // per-state fact lists + prefix
    if (t < Sn) {
        const int s = t;
        const int* q = goals + (b * Sn + s) * (Gn * 3);
        const int qp = q[0], qa0 = q[1], qa1 = q[2];
        const bool v0 = isv(qa0), v1 = isv(qa1);
        const bool active = (qp != PAD);
        const bool vv = active && v0 && v1;
        int nf = 0;
        if (vv) {
            nf = ws[OFF_PN + qp];
        } else if (active) {
            int c = ws[OFF_CNTF + b * Sn + s];
            if (c > KF) c = KF;
            for (int j = 0; j < c; ++j)
                sfx[s * 64 + j] = ws[OFF_UF + (b * Sn + s) * KF + j];
            // insertion sort ascending (reference order = ascending fact idx)
            for (int a = 1; a < c; ++a) {
                const int key = sfx[s * 64 + a];
                int m = a - 1;
                while (m >= 0 && sfx[s * 64 + m] > key) {
                    sfx[s * 64 + m + 1] = sfx[s * 64 + m];
                    m--;
                }
                sfx[s * 64 + m + 1] = key;
            }
            nf = c;
        }
        nfs[s] = nf;
        vvf[s] = vv ? 1 : 0;
        qps[s] = qp;
        int nr = segc[0][s] + segc[1][s] + segc[2][s] + segc[3][s];
        if (nr > KR) nr = KR;
        nrs[s] = nr;

        int incl = nf + nr;
        #pragma unroll
        for (int off = 1; off < 64; off <<= 1) {
            int n = __shfl_up(incl, off, 64);
            if (t >= off) incl += n;
        }
        pref[s + 1] = incl;
        if (s == 0) pref[0] = 0;
    }
    __syncthreads();
    const int total = pref[Sn];

    // emit goals: 64 slots x 8 positions = 512 items, 2 per thread
    for (int item = t; item < Sn * Gn; item += 256) {
        const int i = item >> 3, g = item & 7;
        int trip[3] = {PAD, PAD, PAD};
        if (i < total) {
            int lo = 0, hi = Sn - 1;
            while (lo < hi) {
                const int mid = (lo + hi) >> 1;
                if (pref[mid + 1] <= i) lo = mid + 1; else hi = mid;
            }
            const int s = lo, j = i - pref[s];
            const int* q = goals + (b * Sn + s) * (Gn * 3);
            const int qa0 = q[1], qa1 = q[2];
            if (j < nfs[s]) {
                const int fi = vvf[s] ? ws[OFF_PFIRST + qps[s] * 64 + j]
                                      : sfx[s * 64 + j];
                const int f1 = facts[3 * fi + 1], f2 = facts[3 * fi + 2];
                if (g >= 1) {
                    #pragma unroll
                    for (int c = 0; c < 3; ++c) {
                        int x = q[g * 3 + c];
                        if (isv(qa0) && x == qa0) x = f1;
                        else if (isv(qa1) && x == qa1) x = f2;
                        trip[c] = x;
                    }
                }
            } else {
                int jr = j - nfs[s];
                int wz = 0;
                while (jr >= segc[wz][s]) { jr -= segc[wz][s]; wz++; }
                const int ri = seg[wz][s][jr];
                const int h1 = hds[3 * ri + 1], h2 = hds[3 * ri + 2];
                const int len = rlens[ri];
                if (g < BMAXn) {
                    if (g < len) {
                        #pragma unroll
                        for (int c = 0; c < 3; ++c) {
                            int x = bodies[(ri * BMAXn + g) * 3 + c];
                            if (isv(h1) && x == h1) x = qa0;
                            if (isv(h2) && x == h2) x = qa1;
                            trip[c] = x;
                        }
                    }
                } else {
                    trip[0] = q[(g - 2) * 3 + 0];
                    trip[1] = q[(g - 2) * 3 + 1];
                    trip[2] = q[(g - 2) * 3 + 2];
                }
            }
        }
        float* o = outp + ((b * Sn + i) * Gn + g) * 3;
        o[0] = (float)trip[0];
        o[1] = (float)trip[1];
        o[2] = (float)trip[2];
    }

    // scores
    if (t < Sn) {
        const int i = t;
        float sc = 0.f;
        if (i < total) {
            int lo = 0, hi = Sn - 1;
            while (lo < hi) {
                const int mid = (lo + hi) >> 1;
                if (pref[mid + 1] <= i) lo = mid + 1; else hi = mid;
            }
            const int s = lo, j = i - pref[s];
            const float stt = ss[b * Sn + s];
            if (j < nfs[s]) {
                const int fi = vvf[s] ? ws[OFF_PFIRST + qps[s] * 64 + j]
                                      : sfx[s * 64 + j];
                sc = stt * fsc[fi];
            } else {
                int jr = j - nfs[s];
                int wz = 0;
                while (jr >= segc[wz][s]) { jr -= segc[wz][s]; wz++; }
                sc = stt * rsc[seg[wz][s][jr]];
            }
        }
        outp[Bn * Sn * Gn * 3 + b * Sn + t] = sc;
    }
}

extern "C" void kernel_launch(void* const* d_in, const int* in_sizes, int n_in,
                              void* d_out, int out_size, void* d_ws, size_t ws_size,
                              hipStream_t stream) {
    const int*   goals  = (const int*)  d_in[0];
    const float* ss     = (const float*)d_in[1];
    const int*   facts  = (const int*)  d_in[2];
    const float* fsc    = (const float*)d_in[3];
    const int*   heads  = (const int*)  d_in[4];
    const int*   bodies = (const int*)  d_in[5];
    const int*   rlens  = (const int*)  d_in[6];
    const float* rsc    = (const float*)d_in[7];
    int*   ws   = (int*)d_ws;
    float* outp = (float*)d_out;

    hipMemsetAsync(ws, 0, 512 * sizeof(int), stream);           // zero cntF
    probe_kernel   <<<NBLK + 50, 256, 0, stream>>>(goals, facts, ws);
    finalize_kernel<<<Bn,        256, 0, stream>>>(goals, ss, facts, fsc, heads,
                                                   bodies, rlens, rsc, ws, outp);
}